// Round 1
// baseline (394.406 us; speedup 1.0000x reference)
//
#include <hip/hip_runtime.h>
#include <hip/hip_bf16.h>
#include <stdint.h>

#define TOKENS 16384   // N=4 * L=4096
#define LSEQ 4096

typedef short bf16x8 __attribute__((ext_vector_type(8)));
typedef float f32x4 __attribute__((ext_vector_type(4)));

typedef __attribute__((address_space(1))) void as1_t;
typedef __attribute__((address_space(3))) void as3_t;

__device__ __forceinline__ unsigned short f2bf(float x) {
  __hip_bfloat16 t = __float2bfloat16(x);
  return *reinterpret_cast<unsigned short*>(&t);
}

__device__ __forceinline__ void async16(const void* g, void* lds) {
  __builtin_amdgcn_global_load_lds((as1_t*)const_cast<void*>(g),
                                   (as3_t*)lds, 16, 0, 0);
}

// ---------------- fc_w f32 -> bf16 ----------------
__global__ __launch_bounds__(256) void cvt_bf16(const float* __restrict__ s,
                                                unsigned short* __restrict__ d,
                                                int n4) {
  int i = blockIdx.x * 256 + threadIdx.x;
  if (i < n4) {
    float4 f = ((const float4*)s)[i];
    union { unsigned short us[4]; uint2 u2; } pk;
    pk.us[0] = f2bf(f.x); pk.us[1] = f2bf(f.y);
    pk.us[2] = f2bf(f.z); pk.us[3] = f2bf(f.w);
    ((uint2*)d)[i] = pk.u2;
  }
}

// ---------------- fused projections + per-token 16x16 attention ----------------
// Writes X in (N, H, L, D) layout as bf16 -> flat view equals the scrambled
// (N, L, H*D) matrix the final FC consumes.
__global__ __launch_bounds__(256) void attn_fused(
    const float* __restrict__ q, const float* __restrict__ k,
    const float* __restrict__ v, const int* __restrict__ mask,
    const float* __restrict__ qw, const float* __restrict__ kw,
    const float* __restrict__ vw, unsigned short* __restrict__ X) {
  // weights transposed: sW[e*65 + d] = w[d][e]   (pad 65 -> conflict-free)
  __shared__ float sWq[64 * 65], sWk[64 * 65], sWv[64 * 65];
  __shared__ float sRQ[1024], sRK[1024], sRV[1024];     // raw token rows
  __shared__ float sQ4[16 * 68], sK4[16 * 68], sV4[16 * 68]; // projected (pad 68, 16B-aligned rows)

  const int tid = threadIdx.x;
  const int l = tid & 63, w = tid >> 6;

  for (int idx = tid; idx < 4096; idx += 256) {
    const int d = idx >> 6, e = idx & 63;
    sWq[e * 65 + d] = qw[idx];
    sWk[e * 65 + d] = kw[idx];
    sWv[e * 65 + d] = vw[idx];
  }
  __syncthreads();

  const int hA = tid >> 4;  // 0..15  (logits/out4 phase h)
  const int g  = tid & 15;  // 0..15  (logits g / out4 d-block)

  for (int tok = blockIdx.x; tok < TOKENS; tok += gridDim.x) {
    const int n = tok >> 12;
    const int lpos = tok & (LSEQ - 1);

    // stage raw q/k/v rows (coalesced float4)
    ((float4*)sRQ)[tid] = ((const float4*)(q + (size_t)tok * 1024))[tid];
    ((float4*)sRK)[tid] = ((const float4*)(k + (size_t)tok * 1024))[tid];
    ((float4*)sRV)[tid] = ((const float4*)(v + (size_t)tok * 1024))[tid];
    __syncthreads();

    // projections: wave w computes h in {w, w+4, w+8, w+12}, d = lane
    float aq[4] = {0, 0, 0, 0}, ak[4] = {0, 0, 0, 0}, av[4] = {0, 0, 0, 0};
#pragma unroll 4
    for (int e0 = 0; e0 < 64; e0 += 4) {
      const float wq0 = sWq[(e0 + 0) * 65 + l], wq1 = sWq[(e0 + 1) * 65 + l],
                  wq2 = sWq[(e0 + 2) * 65 + l], wq3 = sWq[(e0 + 3) * 65 + l];
      const float wk0 = sWk[(e0 + 0) * 65 + l], wk1 = sWk[(e0 + 1) * 65 + l],
                  wk2 = sWk[(e0 + 2) * 65 + l], wk3 = sWk[(e0 + 3) * 65 + l];
      const float wv0 = sWv[(e0 + 0) * 65 + l], wv1 = sWv[(e0 + 1) * 65 + l],
                  wv2 = sWv[(e0 + 2) * 65 + l], wv3 = sWv[(e0 + 3) * 65 + l];
#pragma unroll
      for (int i = 0; i < 4; ++i) {
        const int h = w + 4 * i;
        const float4 rq = *(const float4*)&sRQ[h * 64 + e0];
        aq[i] += rq.x * wq0 + rq.y * wq1 + rq.z * wq2 + rq.w * wq3;
        const float4 rk = *(const float4*)&sRK[h * 64 + e0];
        ak[i] += rk.x * wk0 + rk.y * wk1 + rk.z * wk2 + rk.w * wk3;
        const float4 rv = *(const float4*)&sRV[h * 64 + e0];
        av[i] += rv.x * wv0 + rv.y * wv1 + rv.z * wv2 + rv.w * wv3;
      }
    }
#pragma unroll
    for (int i = 0; i < 4; ++i) {
      const int h = w + 4 * i;
      sQ4[h * 68 + l] = aq[i];
      sK4[h * 68 + l] = ak[i];
      sV4[h * 68 + l] = av[i];
    }
    __syncthreads();

    // logits: thread (hA, g) -> dot over d of q4[hA]·k4[g]
    float acc = 0.f;
#pragma unroll
    for (int d0 = 0; d0 < 64; d0 += 4) {
      const float4 a = *(const float4*)&sQ4[hA * 68 + d0];
      const float4 b = *(const float4*)&sK4[g * 68 + d0];
      acc += a.x * b.x + a.y * b.y + a.z * b.z + a.w * b.w;
    }
    acc *= 0.125f;  // 1/sqrt(64)
    if (mask[(size_t)tok * 256 + (hA << 4) + g] == 0) acc = -1e30f;

    // softmax over g (16-lane groups within the wave)
    float mx = acc;
    mx = fmaxf(mx, __shfl_xor(mx, 1));
    mx = fmaxf(mx, __shfl_xor(mx, 2));
    mx = fmaxf(mx, __shfl_xor(mx, 4));
    mx = fmaxf(mx, __shfl_xor(mx, 8));
    const float ex = __expf(acc - mx);
    float sm = ex;
    sm += __shfl_xor(sm, 1);
    sm += __shfl_xor(sm, 2);
    sm += __shfl_xor(sm, 4);
    sm += __shfl_xor(sm, 8);
    const float wsm = ex / sm;

    // out4[hA][d] for d = g*4 .. g*4+3
    float ox = 0.f, oy = 0.f, oz = 0.f, ow = 0.f;
#pragma unroll
    for (int gg = 0; gg < 16; ++gg) {
      const float wg = __shfl(wsm, (l & 48) | gg, 64);
      const float4 vv = *(const float4*)&sV4[gg * 68 + g * 4];
      ox += wg * vv.x; oy += wg * vv.y; oz += wg * vv.z; ow += wg * vv.w;
    }

    // store X in (N, H, L, D) bf16
    union { unsigned short us[4]; uint2 u2; } pk;
    pk.us[0] = f2bf(ox); pk.us[1] = f2bf(oy);
    pk.us[2] = f2bf(oz); pk.us[3] = f2bf(ow);
    *(uint2*)&X[(((size_t)(n * 16 + hA)) * LSEQ + lpos) * 64 + g * 4] = pk.u2;

    __syncthreads();  // protect LDS before next token overwrites
  }
}

// ---------------- final FC: OUT[16384x1024] = X @ fc_w^T + b (bf16 MFMA) ----------------
__global__ __launch_bounds__(256) void gemm_fc(const unsigned short* __restrict__ A,
                                               const unsigned short* __restrict__ B,
                                               const float* __restrict__ bias,
                                               float* __restrict__ C) {
  __shared__ unsigned short sA[128 * 32];
  __shared__ unsigned short sB[128 * 32];
  const int tid = threadIdx.x;
  const int l = tid & 63, w = tid >> 6;
  const int wr = w >> 1, wc = w & 1;

  // bijective XCD swizzle (nwg = 1024, divisible by 8)
  const int bid = blockIdx.x;
  const int wg = (bid & 7) * 128 + (bid >> 3);
  const int tm = (wg >> 3) * 128;
  const int tn = (wg & 7) * 128;

  f32x4 acc[4][4] = {};

  const int r0 = w * 16 + (l >> 2);   // staging row within 64-row half
  const int c8 = (l & 3) * 8;         // staging k-offset (elements)

  for (int kt = 0; kt < 32; ++kt) {
    const int k0 = kt * 32;
#pragma unroll
    for (int s = 0; s < 2; ++s) {
      async16(A + (size_t)(tm + s * 64 + r0) * 1024 + k0 + c8,
              (char*)sA + s * 4096 + w * 1024);
      async16(B + (size_t)(tn + s * 64 + r0) * 1024 + k0 + c8,
              (char*)sB + s * 4096 + w * 1024);
    }
    __syncthreads();

    bf16x8 af[4], bfr[4];
#pragma unroll
    for (int fi = 0; fi < 4; ++fi)
      af[fi] = *(const bf16x8*)((const char*)sA +
                                (wr * 64 + fi * 16 + (l & 15)) * 64 + (l >> 4) * 16);
#pragma unroll
    for (int fj = 0; fj < 4; ++fj)
      bfr[fj] = *(const bf16x8*)((const char*)sB +
                                 (wc * 64 + fj * 16 + (l & 15)) * 64 + (l >> 4) * 16);
#pragma unroll
    for (int fi = 0; fi < 4; ++fi)
#pragma unroll
      for (int fj = 0; fj < 4; ++fj)
        acc[fi][fj] = __builtin_amdgcn_mfma_f32_16x16x32_bf16(af[fi], bfr[fj],
                                                              acc[fi][fj], 0, 0, 0);
    __syncthreads();
  }

#pragma unroll
  for (int fj = 0; fj < 4; ++fj) {
    const int col = tn + wc * 64 + fj * 16 + (l & 15);
    const float bv = bias[col];
#pragma unroll
    for (int fi = 0; fi < 4; ++fi) {
#pragma unroll
      for (int r = 0; r < 4; ++r) {
        const int row = tm + wr * 64 + fi * 16 + (l >> 4) * 4 + r;
        C[(size_t)row * 1024 + col] = acc[fi][fj][r] + bv;
      }
    }
  }
}

extern "C" void kernel_launch(void* const* d_in, const int* in_sizes, int n_in,
                              void* d_out, int out_size, void* d_ws, size_t ws_size,
                              hipStream_t stream) {
  (void)in_sizes; (void)n_in; (void)out_size; (void)ws_size;
  const float* q   = (const float*)d_in[0];
  const float* k   = (const float*)d_in[1];
  const float* v   = (const float*)d_in[2];
  const int*  mask = (const int*)d_in[3];
  const float* qw  = (const float*)d_in[4];
  const float* kw  = (const float*)d_in[5];
  const float* vw  = (const float*)d_in[6];
  const float* fcw = (const float*)d_in[7];
  const float* fcb = (const float*)d_in[8];
  float* out = (float*)d_out;

  unsigned short* X  = (unsigned short*)d_ws;            // 16M bf16 = 32 MiB
  unsigned short* Wb = X + (size_t)16 * 1024 * 1024;     // 1M bf16  =  2 MiB

  cvt_bf16<<<dim3(1024), dim3(256), 0, stream>>>(fcw, Wb, 262144);
  attn_fused<<<dim3(2048), dim3(256), 0, stream>>>(q, k, v, mask, qw, kw, vw, X);
  gemm_fc<<<dim3(1024), dim3(256), 0, stream>>>(X, Wb, fcb, out);
}

// Round 2
// 145.587 us; speedup vs baseline: 2.7091x; 2.7091x over previous
//
#include <hip/hip_runtime.h>
#include <hip/hip_bf16.h>
#include <stdint.h>

#define TOKENS 16384   // N=4 * L=4096
#define LSEQ 4096

typedef short bf16x8 __attribute__((ext_vector_type(8)));
typedef float f32x4 __attribute__((ext_vector_type(4)));

typedef __attribute__((address_space(1))) void as1_t;
typedef __attribute__((address_space(3))) void as3_t;

__device__ __forceinline__ unsigned short f2bf(float x) {
  __hip_bfloat16 t = __float2bfloat16(x);
  return *reinterpret_cast<unsigned short*>(&t);
}

__device__ __forceinline__ bf16x8 pack8(float4 a, float4 b) {
  bf16x8 t;
  t[0] = (short)f2bf(a.x); t[1] = (short)f2bf(a.y);
  t[2] = (short)f2bf(a.z); t[3] = (short)f2bf(a.w);
  t[4] = (short)f2bf(b.x); t[5] = (short)f2bf(b.y);
  t[6] = (short)f2bf(b.z); t[7] = (short)f2bf(b.w);
  return t;
}

__device__ __forceinline__ void async16(const void* g, void* lds) {
  __builtin_amdgcn_global_load_lds((as1_t*)const_cast<void*>(g),
                                   (as3_t*)lds, 16, 0, 0);
}

// ---------------- fc_w f32 -> bf16 ----------------
__global__ __launch_bounds__(256) void cvt_bf16(const float* __restrict__ s,
                                                unsigned short* __restrict__ d,
                                                int n4) {
  int i = blockIdx.x * 256 + threadIdx.x;
  if (i < n4) {
    float4 f = ((const float4*)s)[i];
    union { unsigned short us[4]; uint2 u2; } pk;
    pk.us[0] = f2bf(f.x); pk.us[1] = f2bf(f.y);
    pk.us[2] = f2bf(f.z); pk.us[3] = f2bf(f.w);
    ((uint2*)d)[i] = pk.u2;
  }
}

// ---------------- fused MFMA projections + per-token 16x16 attention ----------------
// One token per wave; no __syncthreads anywhere. Wave-private LDS regions.
// q4/k4 LDS rows: 64 bf16 (128B) padded to 144B. v4T rows: 16 bf16 (32B) padded to 48B.
#define STQ_US 72   // ushorts per q4/k4 row (144B)
#define STV_US 24   // ushorts per v4T row (48B)
#define WAVE_LDS 7680  // 16*144 + 16*144 + 64*48

__global__ __launch_bounds__(256, 2) void attn_fused2(
    const float* __restrict__ q, const float* __restrict__ k,
    const float* __restrict__ v, const int* __restrict__ mask,
    const float* __restrict__ qw, const float* __restrict__ kw,
    const float* __restrict__ vw, unsigned short* __restrict__ X) {
  __shared__ char lds_all[4 * WAVE_LDS];
  const int tid = threadIdx.x;
  const int l = tid & 63, w = tid >> 6;
  const int lr = l & 15, lg = l >> 4;
  char* wl = &lds_all[w * WAVE_LDS];
  unsigned short* q4l = (unsigned short*)(wl);
  unsigned short* k4l = (unsigned short*)(wl + 2304);
  unsigned short* v4l = (unsigned short*)(wl + 4608);

  // Weight B-fragments, held in registers: wf[arr][ntile][kc]
  // B[k=e][col=dout] = W[dout][e] -> lane: W[n*16+lr][kc*32+lg*8 + j]
  bf16x8 wf[3][4][2];
  {
    const float* ws[3] = {qw, kw, vw};
#pragma unroll
    for (int a = 0; a < 3; ++a)
#pragma unroll
      for (int n = 0; n < 4; ++n)
#pragma unroll
        for (int kc = 0; kc < 2; ++kc) {
          const float* p = ws[a] + (n * 16 + lr) * 64 + kc * 32 + lg * 8;
          wf[a][n][kc] = pack8(*(const float4*)p, *(const float4*)(p + 4));
        }
  }

  const int gw = blockIdx.x * 4 + w;   // 0..8191
#pragma unroll 1
  for (int it = 0; it < 2; ++it) {
    const int tok = gw + it * 8192;
    const size_t tb = (size_t)tok * 1024;
    const int off = lr * 64 + lg * 8;

    // ---- issue all global loads up front ----
    float4 qa = *(const float4*)(q + tb + off);
    float4 qb = *(const float4*)(q + tb + off + 4);
    float4 qc = *(const float4*)(q + tb + off + 32);
    float4 qd = *(const float4*)(q + tb + off + 36);
    float4 ka_ = *(const float4*)(k + tb + off);
    float4 kb_ = *(const float4*)(k + tb + off + 4);
    float4 kc_ = *(const float4*)(k + tb + off + 32);
    float4 kd_ = *(const float4*)(k + tb + off + 36);
    float4 va = *(const float4*)(v + tb + off);
    float4 vb = *(const float4*)(v + tb + off + 4);
    float4 vc = *(const float4*)(v + tb + off + 32);
    float4 vd = *(const float4*)(v + tb + off + 36);
    int mk[4];
#pragma unroll
    for (int r = 0; r < 4; ++r)
      mk[r] = mask[(size_t)tok * 256 + lr * 16 + lg * 4 + r];

    // ---- projections via MFMA: q4/k4/v4[h][dout], h=lg*4+r, dout=n*16+lr ----
    bf16x8 aq0 = pack8(qa, qb), aq1 = pack8(qc, qd);
    bf16x8 ak0 = pack8(ka_, kb_), ak1 = pack8(kc_, kd_);
    bf16x8 av0 = pack8(va, vb), av1 = pack8(vc, vd);
    f32x4 accq[4], acck[4], accv[4];
#pragma unroll
    for (int n = 0; n < 4; ++n) {
      f32x4 z = {};
      accq[n] = __builtin_amdgcn_mfma_f32_16x16x32_bf16(aq0, wf[0][n][0], z, 0, 0, 0);
      accq[n] = __builtin_amdgcn_mfma_f32_16x16x32_bf16(aq1, wf[0][n][1], accq[n], 0, 0, 0);
      acck[n] = __builtin_amdgcn_mfma_f32_16x16x32_bf16(ak0, wf[1][n][0], z, 0, 0, 0);
      acck[n] = __builtin_amdgcn_mfma_f32_16x16x32_bf16(ak1, wf[1][n][1], acck[n], 0, 0, 0);
      accv[n] = __builtin_amdgcn_mfma_f32_16x16x32_bf16(av0, wf[2][n][0], z, 0, 0, 0);
      accv[n] = __builtin_amdgcn_mfma_f32_16x16x32_bf16(av1, wf[2][n][1], accv[n], 0, 0, 0);
    }

    // ---- spill q4/k4 (row-major [h][d]) and v4 transposed ([d][g]) to LDS ----
#pragma unroll
    for (int n = 0; n < 4; ++n)
#pragma unroll
      for (int r = 0; r < 4; ++r) {
        q4l[(lg * 4 + r) * STQ_US + n * 16 + lr] = f2bf(accq[n][r]);
        k4l[(lg * 4 + r) * STQ_US + n * 16 + lr] = f2bf(acck[n][r]);
        v4l[(n * 16 + lr) * STV_US + lg * 4 + r] = f2bf(accv[n][r]);
      }

    // ---- S^T = k4 @ q4^T  (C: col=h=lr, row=g=lg*4+r) ----
    bf16x8 sa0 = *(const bf16x8*)(k4l + lr * STQ_US + lg * 8);
    bf16x8 sa1 = *(const bf16x8*)(k4l + lr * STQ_US + 32 + lg * 8);
    bf16x8 sb0 = *(const bf16x8*)(q4l + lr * STQ_US + lg * 8);
    bf16x8 sb1 = *(const bf16x8*)(q4l + lr * STQ_US + 32 + lg * 8);
    f32x4 z4 = {};
    f32x4 st = __builtin_amdgcn_mfma_f32_16x16x32_bf16(sa0, sb0, z4, 0, 0, 0);
    st = __builtin_amdgcn_mfma_f32_16x16x32_bf16(sa1, sb1, st, 0, 0, 0);

    // ---- softmax over g (in-lane 4 + lane-groups 16/32) ----
    float sv[4];
#pragma unroll
    for (int r = 0; r < 4; ++r)
      sv[r] = (mk[r] != 0) ? st[r] * 0.125f : -1e30f;
    float mx = fmaxf(fmaxf(sv[0], sv[1]), fmaxf(sv[2], sv[3]));
    mx = fmaxf(mx, __shfl_xor(mx, 16));
    mx = fmaxf(mx, __shfl_xor(mx, 32));
    float e[4];
    float sm = 0.f;
#pragma unroll
    for (int r = 0; r < 4; ++r) { e[r] = __expf(sv[r] - mx); sm += e[r]; }
    sm += __shfl_xor(sm, 16);
    sm += __shfl_xor(sm, 32);
    const float inv = 1.0f / sm;
#pragma unroll
    for (int r = 0; r < 4; ++r) e[r] *= inv;

    // ---- build PV A-fragment: lane needs P[h=lr][g=lg*8+j] (lanes>=32 zero) ----
    bf16x8 apv;
#pragma unroll
    for (int j = 0; j < 8; ++j) {
      const int srcg = (lg * 2 + (j >> 2)) & 3;
      const float pv = __shfl(e[j & 3], lr + srcg * 16, 64);
      apv[j] = (short)((lg < 2) ? f2bf(pv) : (unsigned short)0);
    }

    // ---- PV: O = P @ v4 (K=16 zero-padded to 32) ----
    f32x4 o[4];
#pragma unroll
    for (int n = 0; n < 4; ++n) {
      bf16x8 bv = *(const bf16x8*)(v4l + (n * 16 + lr) * STV_US + (lg & 1) * 8);
      f32x4 z = {};
      o[n] = __builtin_amdgcn_mfma_f32_16x16x32_bf16(apv, bv, z, 0, 0, 0);
    }

    // ---- store X in (N,H,L,D) bf16 ----
    const int nb = tok >> 12, lpos = tok & (LSEQ - 1);
#pragma unroll
    for (int n = 0; n < 4; ++n)
#pragma unroll
      for (int r = 0; r < 4; ++r) {
        const int h = lg * 4 + r, d = n * 16 + lr;
        X[((size_t)(nb * 16 + h) * LSEQ + lpos) * 64 + d] = f2bf(o[n][r]);
      }
  }
}

// ---------------- final FC: OUT[16384x1024] = X @ fc_w^T + b (bf16 MFMA) ----------------
__global__ __launch_bounds__(256) void gemm_fc(const unsigned short* __restrict__ A,
                                               const unsigned short* __restrict__ B,
                                               const float* __restrict__ bias,
                                               float* __restrict__ C) {
  __shared__ unsigned short sA[128 * 32];
  __shared__ unsigned short sB[128 * 32];
  const int tid = threadIdx.x;
  const int l = tid & 63, w = tid >> 6;
  const int wr = w >> 1, wc = w & 1;

  // bijective XCD swizzle (nwg = 1024, divisible by 8)
  const int bid = blockIdx.x;
  const int wg = (bid & 7) * 128 + (bid >> 3);
  const int tm = (wg >> 3) * 128;
  const int tn = (wg & 7) * 128;

  f32x4 acc[4][4] = {};

  const int r0 = w * 16 + (l >> 2);   // staging row within 64-row half
  const int c8 = (l & 3) * 8;         // staging k-offset (elements)

  for (int kt = 0; kt < 32; ++kt) {
    const int k0 = kt * 32;
#pragma unroll
    for (int s = 0; s < 2; ++s) {
      async16(A + (size_t)(tm + s * 64 + r0) * 1024 + k0 + c8,
              (char*)sA + s * 4096 + w * 1024);
      async16(B + (size_t)(tn + s * 64 + r0) * 1024 + k0 + c8,
              (char*)sB + s * 4096 + w * 1024);
    }
    __syncthreads();

    bf16x8 af[4], bfr[4];
#pragma unroll
    for (int fi = 0; fi < 4; ++fi)
      af[fi] = *(const bf16x8*)((const char*)sA +
                                (wr * 64 + fi * 16 + (l & 15)) * 64 + (l >> 4) * 16);
#pragma unroll
    for (int fj = 0; fj < 4; ++fj)
      bfr[fj] = *(const bf16x8*)((const char*)sB +
                                 (wc * 64 + fj * 16 + (l & 15)) * 64 + (l >> 4) * 16);
#pragma unroll
    for (int fi = 0; fi < 4; ++fi)
#pragma unroll
      for (int fj = 0; fj < 4; ++fj)
        acc[fi][fj] = __builtin_amdgcn_mfma_f32_16x16x32_bf16(af[fi], bfr[fj],
                                                              acc[fi][fj], 0, 0, 0);
    __syncthreads();
  }

#pragma unroll
  for (int fj = 0; fj < 4; ++fj) {
    const int col = tn + wc * 64 + fj * 16 + (l & 15);
    const float bv = bias[col];
#pragma unroll
    for (int fi = 0; fi < 4; ++fi) {
#pragma unroll
      for (int r = 0; r < 4; ++r) {
        const int row = tm + wr * 64 + fi * 16 + (l >> 4) * 4 + r;
        C[(size_t)row * 1024 + col] = acc[fi][fj][r] + bv;
      }
    }
  }
}

extern "C" void kernel_launch(void* const* d_in, const int* in_sizes, int n_in,
                              void* d_out, int out_size, void* d_ws, size_t ws_size,
                              hipStream_t stream) {
  (void)in_sizes; (void)n_in; (void)out_size; (void)ws_size;
  const float* q   = (const float*)d_in[0];
  const float* k   = (const float*)d_in[1];
  const float* v   = (const float*)d_in[2];
  const int*  mask = (const int*)d_in[3];
  const float* qw  = (const float*)d_in[4];
  const float* kw  = (const float*)d_in[5];
  const float* vw  = (const float*)d_in[6];
  const float* fcw = (const float*)d_in[7];
  const float* fcb = (const float*)d_in[8];
  float* out = (float*)d_out;

  unsigned short* X  = (unsigned short*)d_ws;            // 16M bf16 = 32 MiB
  unsigned short* Wb = X + (size_t)16 * 1024 * 1024;     // 1M bf16  =  2 MiB

  cvt_bf16<<<dim3(1024), dim3(256), 0, stream>>>(fcw, Wb, 262144);
  attn_fused2<<<dim3(2048), dim3(256), 0, stream>>>(q, k, v, mask, qw, kw, vw, X);
  gemm_fc<<<dim3(1024), dim3(256), 0, stream>>>(X, Wb, fcb, out);
}

// Round 3
// 112.982 us; speedup vs baseline: 3.4909x; 1.2886x over previous
//
#include <hip/hip_runtime.h>
#include <hip/hip_bf16.h>
#include <stdint.h>

#define TOKENS 16384   // N=4 * L=4096
#define LSEQ 4096
#define WPAD 72        // padded row length (shorts) for M/vw/U/o tiles
#define VPAD 24        // padded row length (shorts) for v4T tile

typedef short bf16x8 __attribute__((ext_vector_type(8)));
typedef float f32x4 __attribute__((ext_vector_type(4)));

typedef __attribute__((address_space(1))) void as1_t;
typedef __attribute__((address_space(3))) void as3_t;

__device__ __forceinline__ unsigned short f2bf(float x) {
  __hip_bfloat16 t = __float2bfloat16(x);
  return *reinterpret_cast<unsigned short*>(&t);
}

__device__ __forceinline__ bf16x8 pack8(float4 a, float4 b) {
  bf16x8 t;
  t[0] = (short)f2bf(a.x); t[1] = (short)f2bf(a.y);
  t[2] = (short)f2bf(a.z); t[3] = (short)f2bf(a.w);
  t[4] = (short)f2bf(b.x); t[5] = (short)f2bf(b.y);
  t[6] = (short)f2bf(b.z); t[7] = (short)f2bf(b.w);
  return t;
}

__device__ __forceinline__ void async16(const void* g, void* lds) {
  __builtin_amdgcn_global_load_lds((as1_t*)const_cast<void*>(g),
                                   (as3_t*)lds, 16, 0, 0);
}

// ---------------- fc_w f32 -> bf16 ----------------
__global__ __launch_bounds__(256) void cvt_bf16(const float* __restrict__ s,
                                                unsigned short* __restrict__ d,
                                                int n4) {
  int i = blockIdx.x * 256 + threadIdx.x;
  if (i < n4) {
    float4 f = ((const float4*)s)[i];
    union { unsigned short us[4]; uint2 u2; } pk;
    pk.us[0] = f2bf(f.x); pk.us[1] = f2bf(f.y);
    pk.us[2] = f2bf(f.z); pk.us[3] = f2bf(f.w);
    ((uint2*)d)[i] = pk.u2;
  }
}

// ---------------- prep: M[f][e] = sum_d qw[d][f]*kw[d][e]; vw -> bf16 ----------------
__global__ __launch_bounds__(1024) void prep_weights(
    const float* __restrict__ qw, const float* __restrict__ kw,
    const float* __restrict__ vw, unsigned short* __restrict__ Mout,
    unsigned short* __restrict__ vwout) {
  __shared__ float ql[4096], kl[4096];
  const int t = threadIdx.x;
  ((float4*)ql)[t] = ((const float4*)qw)[t];
  ((float4*)kl)[t] = ((const float4*)kw)[t];
  // vw convert (independent of LDS)
  {
    float4 f = ((const float4*)vw)[t];
    union { unsigned short us[4]; uint2 u2; } pk;
    pk.us[0] = f2bf(f.x); pk.us[1] = f2bf(f.y);
    pk.us[2] = f2bf(f.z); pk.us[3] = f2bf(f.w);
    ((uint2*)vwout)[t] = pk.u2;
  }
  __syncthreads();
  const int f = t >> 4;            // 0..63  (q raw dim)
  const int e0 = (t & 15) * 4;     // 0..60  (k raw dim block)
  float acc0 = 0.f, acc1 = 0.f, acc2 = 0.f, acc3 = 0.f;
#pragma unroll 8
  for (int d = 0; d < 64; ++d) {
    const float qv = ql[d * 64 + f];
    const float4 kv = *(const float4*)&kl[d * 64 + e0];
    acc0 += qv * kv.x; acc1 += qv * kv.y; acc2 += qv * kv.z; acc3 += qv * kv.w;
  }
  union { unsigned short us[4]; uint2 u2; } pk;
  pk.us[0] = f2bf(acc0); pk.us[1] = f2bf(acc1);
  pk.us[2] = f2bf(acc2); pk.us[3] = f2bf(acc3);
  *(uint2*)&Mout[f * 64 + e0] = pk.u2;
}

// ---------------- fused attention: one token per wave ----------------
// S^T = (Rk @ M^T) @ Rq^T ; v4 = Rv @ vw^T ; O = softmax(S)^T-applied @ v4.
// mfma convention (HW-validated R2): mfma(fragA(X), fragA(Y)) = X @ Y^T,
// fragA: lane holds X[row=l&15][k=(l>>4)*8+j].
__global__ __launch_bounds__(256, 4) void attn3(
    const float* __restrict__ q, const float* __restrict__ k,
    const float* __restrict__ v, const int* __restrict__ mask,
    const unsigned short* __restrict__ Mg, const unsigned short* __restrict__ vwg,
    unsigned short* __restrict__ X) {
  __shared__ unsigned short Ml[64 * WPAD];        // 9216 B
  __shared__ unsigned short Vw[64 * WPAD];        // 9216 B
  __shared__ unsigned short scr[4][16 * WPAD];    // U then o (per wave)
  __shared__ unsigned short v4t[4][64 * VPAD];    // v4 transposed (per wave)

  const int tid = threadIdx.x;
  const int l = tid & 63, w = tid >> 6;
  const int lr = l & 15, lg = l >> 4;

  const int tok = blockIdx.x * 4 + w;
  const size_t tb = (size_t)tok * 1024;
  const int off = lr * 64 + lg * 8;

  // ---- issue data loads first (long pole) ----
  const float4 qa = *(const float4*)(q + tb + off);
  const float4 qb = *(const float4*)(q + tb + off + 4);
  const float4 qc = *(const float4*)(q + tb + off + 32);
  const float4 qd = *(const float4*)(q + tb + off + 36);
  const float4 ka = *(const float4*)(k + tb + off);
  const float4 kb = *(const float4*)(k + tb + off + 4);
  const float4 kc = *(const float4*)(k + tb + off + 32);
  const float4 kd = *(const float4*)(k + tb + off + 36);
  const float4 va = *(const float4*)(v + tb + off);
  const float4 vb = *(const float4*)(v + tb + off + 4);
  const float4 vc = *(const float4*)(v + tb + off + 32);
  const float4 vd = *(const float4*)(v + tb + off + 36);
  const int4 mk4 = *(const int4*)(mask + (size_t)tok * 256 + lr * 16 + lg * 4);

  // ---- stage weights into LDS (block-wide, once) ----
  {
    const int row = tid >> 2, c0 = (tid & 3) * 16;
    *(uint4*)&Ml[row * WPAD + c0]     = *(const uint4*)(Mg + row * 64 + c0);
    *(uint4*)&Ml[row * WPAD + c0 + 8] = *(const uint4*)(Mg + row * 64 + c0 + 8);
    *(uint4*)&Vw[row * WPAD + c0]     = *(const uint4*)(vwg + row * 64 + c0);
    *(uint4*)&Vw[row * WPAD + c0 + 8] = *(const uint4*)(vwg + row * 64 + c0 + 8);
  }
  __syncthreads();

  // ---- pack raw fragments ----
  const bf16x8 ak0 = pack8(ka, kb), ak1 = pack8(kc, kd);
  const bf16x8 av0 = pack8(va, vb), av1 = pack8(vc, vd);
  const bf16x8 aq0 = pack8(qa, qb), aq1 = pack8(qc, qd);

  // ---- U = Rk @ M^T ; v4 = Rv @ vw^T ----
  f32x4 accu[4], accv[4];
#pragma unroll
  for (int n = 0; n < 4; ++n) {
    const int wrow = (n * 16 + lr) * WPAD;
    f32x4 z = {};
    bf16x8 bm0 = *(const bf16x8*)&Ml[wrow + lg * 8];
    bf16x8 bm1 = *(const bf16x8*)&Ml[wrow + 32 + lg * 8];
    accu[n] = __builtin_amdgcn_mfma_f32_16x16x32_bf16(ak0, bm0, z, 0, 0, 0);
    accu[n] = __builtin_amdgcn_mfma_f32_16x16x32_bf16(ak1, bm1, accu[n], 0, 0, 0);
    bf16x8 bw0 = *(const bf16x8*)&Vw[wrow + lg * 8];
    bf16x8 bw1 = *(const bf16x8*)&Vw[wrow + 32 + lg * 8];
    accv[n] = __builtin_amdgcn_mfma_f32_16x16x32_bf16(av0, bw0, z, 0, 0, 0);
    accv[n] = __builtin_amdgcn_mfma_f32_16x16x32_bf16(av1, bw1, accv[n], 0, 0, 0);
  }

  // ---- spill U (row-major [g][e]) and v4 transposed ([d][g]) ----
  unsigned short* U = scr[w];
  unsigned short* VT = v4t[w];
#pragma unroll
  for (int n = 0; n < 4; ++n)
#pragma unroll
    for (int r = 0; r < 4; ++r) {
      U[(lg * 4 + r) * WPAD + n * 16 + lr] = f2bf(accu[n][r]);
      VT[(n * 16 + lr) * VPAD + lg * 4 + r] = f2bf(accv[n][r]);
    }

  // ---- S^T = U @ Rq^T  (C: row=g=lg*4+r, col=h=lr) ----
  const bf16x8 ua0 = *(const bf16x8*)&U[lr * WPAD + lg * 8];
  const bf16x8 ua1 = *(const bf16x8*)&U[lr * WPAD + 32 + lg * 8];
  f32x4 z4 = {};
  f32x4 st = __builtin_amdgcn_mfma_f32_16x16x32_bf16(ua0, aq0, z4, 0, 0, 0);
  st = __builtin_amdgcn_mfma_f32_16x16x32_bf16(ua1, aq1, st, 0, 0, 0);

  // ---- softmax over g ----
  const int mk[4] = {mk4.x, mk4.y, mk4.z, mk4.w};
  float sv[4];
#pragma unroll
  for (int r = 0; r < 4; ++r)
    sv[r] = (mk[r] != 0) ? st[r] * 0.125f : -1e30f;
  float mx = fmaxf(fmaxf(sv[0], sv[1]), fmaxf(sv[2], sv[3]));
  mx = fmaxf(mx, __shfl_xor(mx, 16));
  mx = fmaxf(mx, __shfl_xor(mx, 32));
  float e[4];
  float sm = 0.f;
#pragma unroll
  for (int r = 0; r < 4; ++r) { e[r] = __expf(sv[r] - mx); sm += e[r]; }
  sm += __shfl_xor(sm, 16);
  sm += __shfl_xor(sm, 32);
  const float inv = 1.0f / sm;
#pragma unroll
  for (int r = 0; r < 4; ++r) e[r] *= inv;

  // ---- PV A-fragment: lane needs P[h=lr][g=lg*8+j] (lanes lg>=2 zero) ----
  bf16x8 apv;
#pragma unroll
  for (int j = 0; j < 8; ++j) {
    const int srcg = (lg * 2 + (j >> 2)) & 3;
    const float pv = __shfl(e[j & 3], lr + srcg * 16, 64);
    apv[j] = (short)((lg < 2) ? f2bf(pv) : (unsigned short)0);
  }

  // ---- O = P @ v4 (K=16 zero-padded to 32) ----
  f32x4 o[4];
#pragma unroll
  for (int n = 0; n < 4; ++n) {
    bf16x8 bv = *(const bf16x8*)&VT[(n * 16 + lr) * VPAD + (lg & 1) * 8];
    f32x4 z = {};
    o[n] = __builtin_amdgcn_mfma_f32_16x16x32_bf16(apv, bv, z, 0, 0, 0);
  }

  // ---- transpose O through LDS (reuse U region), then vector stores ----
#pragma unroll
  for (int n = 0; n < 4; ++n)
#pragma unroll
    for (int r = 0; r < 4; ++r)
      U[(lg * 4 + r) * WPAD + n * 16 + lr] = f2bf(o[n][r]);

  const int nb = tok >> 12, lpos = tok & (LSEQ - 1);
#pragma unroll
  for (int it = 0; it < 2; ++it) {
    const int idx = it * 64 + l;
    const int h = idx >> 3, c = idx & 7;
    const uint4 val = *(const uint4*)&U[h * WPAD + c * 8];
    *(uint4*)&X[((size_t)(nb * 16 + h) * LSEQ + lpos) * 64 + c * 8] = val;
  }
}

// ---------------- final FC: OUT[16384x1024] = X @ fc_w^T + b (bf16 MFMA) ----------------
__global__ __launch_bounds__(256) void gemm_fc(const unsigned short* __restrict__ A,
                                               const unsigned short* __restrict__ B,
                                               const float* __restrict__ bias,
                                               float* __restrict__ C) {
  __shared__ unsigned short sA[128 * 32];
  __shared__ unsigned short sB[128 * 32];
  const int tid = threadIdx.x;
  const int l = tid & 63, w = tid >> 6;
  const int wr = w >> 1, wc = w & 1;

  const int bid = blockIdx.x;
  const int wg = (bid & 7) * 128 + (bid >> 3);
  const int tm = (wg >> 3) * 128;
  const int tn = (wg & 7) * 128;

  f32x4 acc[4][4] = {};

  const int r0 = w * 16 + (l >> 2);
  const int c8 = (l & 3) * 8;

  for (int kt = 0; kt < 32; ++kt) {
    const int k0 = kt * 32;
#pragma unroll
    for (int s = 0; s < 2; ++s) {
      async16(A + (size_t)(tm + s * 64 + r0) * 1024 + k0 + c8,
              (char*)sA + s * 4096 + w * 1024);
      async16(B + (size_t)(tn + s * 64 + r0) * 1024 + k0 + c8,
              (char*)sB + s * 4096 + w * 1024);
    }
    __syncthreads();

    bf16x8 af[4], bfr[4];
#pragma unroll
    for (int fi = 0; fi < 4; ++fi)
      af[fi] = *(const bf16x8*)((const char*)sA +
                                (wr * 64 + fi * 16 + (l & 15)) * 64 + (l >> 4) * 16);
#pragma unroll
    for (int fj = 0; fj < 4; ++fj)
      bfr[fj] = *(const bf16x8*)((const char*)sB +
                                 (wc * 64 + fj * 16 + (l & 15)) * 64 + (l >> 4) * 16);
#pragma unroll
    for (int fi = 0; fi < 4; ++fi)
#pragma unroll
      for (int fj = 0; fj < 4; ++fj)
        acc[fi][fj] = __builtin_amdgcn_mfma_f32_16x16x32_bf16(af[fi], bfr[fj],
                                                              acc[fi][fj], 0, 0, 0);
    __syncthreads();
  }

#pragma unroll
  for (int fj = 0; fj < 4; ++fj) {
    const int col = tn + wc * 64 + fj * 16 + (l & 15);
    const float bv = bias[col];
#pragma unroll
    for (int fi = 0; fi < 4; ++fi) {
#pragma unroll
      for (int r = 0; r < 4; ++r) {
        const int row = tm + wr * 64 + fi * 16 + (l >> 4) * 4 + r;
        C[(size_t)row * 1024 + col] = acc[fi][fj][r] + bv;
      }
    }
  }
}

extern "C" void kernel_launch(void* const* d_in, const int* in_sizes, int n_in,
                              void* d_out, int out_size, void* d_ws, size_t ws_size,
                              hipStream_t stream) {
  (void)in_sizes; (void)n_in; (void)out_size; (void)ws_size;
  const float* q   = (const float*)d_in[0];
  const float* k   = (const float*)d_in[1];
  const float* v   = (const float*)d_in[2];
  const int*  mask = (const int*)d_in[3];
  const float* qw  = (const float*)d_in[4];
  const float* kw  = (const float*)d_in[5];
  const float* vw  = (const float*)d_in[6];
  const float* fcw = (const float*)d_in[7];
  const float* fcb = (const float*)d_in[8];
  float* out = (float*)d_out;

  unsigned short* X   = (unsigned short*)d_ws;            // 16M bf16 = 32 MiB
  unsigned short* Wb  = X + (size_t)16 * 1024 * 1024;     // 1M bf16  =  2 MiB
  unsigned short* Mw  = Wb + (size_t)1024 * 1024;         // 4096 bf16 = 8 KiB
  unsigned short* vwb = Mw + 4096;                        // 4096 bf16 = 8 KiB

  cvt_bf16<<<dim3(1024), dim3(256), 0, stream>>>(fcw, Wb, 262144);
  prep_weights<<<dim3(1), dim3(1024), 0, stream>>>(qw, kw, vw, Mw, vwb);
  attn3<<<dim3(4096), dim3(256), 0, stream>>>(q, k, v, mask, Mw, vwb, X);
  gemm_fc<<<dim3(1024), dim3(256), 0, stream>>>(X, Wb, fcb, out);
}